// Round 9
// baseline (103.009 us; speedup 1.0000x reference)
//
#include <hip/hip_runtime.h>
#include <hip/hip_bf16.h>
#include <math.h>

#define NH 8
#define C_ 512
#define C3 1536
#define NTOK 16384   // b*t*h*w = 2*8*32*32

typedef __attribute__((ext_vector_type(8))) short short8;
typedef __attribute__((ext_vector_type(4))) float f32x4;
typedef __attribute__((address_space(3))) void* lds_ptr_t;
typedef const __attribute__((address_space(1))) void* gbl_ptr_t;

static __device__ __forceinline__ ushort f2bf(float f) {
  __hip_bfloat16 h = __float2bfloat16(f);
  return *reinterpret_cast<ushort*>(&h);
}
static __device__ __forceinline__ float bf2f(ushort u) {
  uint t = ((uint)u) << 16;
  float f;
  __builtin_memcpy(&f, &t, 4);
  return f;
}

#define GLD16(src, dst) \
  __builtin_amdgcn_global_load_lds((gbl_ptr_t)(const void*)(src), (lds_ptr_t)(dst), 16, 0, 0)

// ---------------------------------------------------------------------------
// K0: fused fp32 -> bf16 cast for x, w_in, w_out PLUS cos/sin table for rope.
// ---------------------------------------------------------------------------
__global__ __launch_bounds__(256) void cast3_kernel(
    const float* __restrict__ x, const float* __restrict__ wi,
    const float* __restrict__ wo, const float* __restrict__ fr,
    ushort* __restrict__ xb, ushort* __restrict__ wib,
    ushort* __restrict__ wob, float2* __restrict__ csn) {
  const int blk = blockIdx.x;
  if (blk >= 4608) {   // 128 blocks: sincos table (8 entries/thread)
    int i = (blk - 4608) * 256 + threadIdx.x;
    const float4* fp = (const float4*)fr + (size_t)i * 2;
    float4 a = fp[0], b = fp[1];
    float v[8] = {a.x, a.y, a.z, a.w, b.x, b.y, b.z, b.w};
    float2 o[8];
#pragma unroll
    for (int j = 0; j < 8; ++j) { o[j].x = cosf(v[j]); o[j].y = sinf(v[j]); }
    float4* op = (float4*)(csn + (size_t)i * 8);
    op[0] = make_float4(o[0].x, o[0].y, o[1].x, o[1].y);
    op[1] = make_float4(o[2].x, o[2].y, o[3].x, o[3].y);
    op[2] = make_float4(o[4].x, o[4].y, o[5].x, o[5].y);
    op[3] = make_float4(o[6].x, o[6].y, o[7].x, o[7].y);
    return;
  }
  const float* src;
  ushort* dst;
  int i;
  if (blk < 4096)      { src = x;  dst = xb;  i = blk * 256 + threadIdx.x; }
  else if (blk < 4480) { src = wi; dst = wib; i = (blk - 4096) * 256 + threadIdx.x; }
  else                 { src = wo; dst = wob; i = (blk - 4480) * 256 + threadIdx.x; }
  const float4* p = (const float4*)src + (size_t)i * 2;
  float4 v0 = p[0], v1 = p[1];
  union { ushort u[8]; uint4 v; } r;
  r.u[0] = f2bf(v0.x); r.u[1] = f2bf(v0.y); r.u[2] = f2bf(v0.z); r.u[3] = f2bf(v0.w);
  r.u[4] = f2bf(v1.x); r.u[5] = f2bf(v1.y); r.u[6] = f2bf(v1.z); r.u[7] = f2bf(v1.w);
  *(uint4*)(dst + (size_t)i * 8) = r.v;
}

// ---------------------------------------------------------------------------
// K1: qkv GEMM, 256x128x32 tile / 512 threads (8 waves), launch_bounds(512,3)
// (arg-2 = min BLOCKS per CU on this toolchain — R6 erratum). Unchanged R7.
// ---------------------------------------------------------------------------
#define QBM 256
#define QBN 128
#define QBK 32
#define QTILE 12288   // (256+128)*32 ushorts per buffer

static __device__ __forceinline__ void stage_q256(
    const ushort* __restrict__ A, const ushort* __restrict__ B,
    ushort* As, ushort* Bs, int bm, int bn, int K, int k0, int tid) {
#pragma unroll
  for (int it = 0; it < 2; ++it) {
    int c = it * 512 + tid;
    int row = c >> 2;
    int sk = ((c & 3) ^ ((row >> 1) & 3)) * 8;
    GLD16(A + (size_t)(bm + row) * K + k0 + sk, As + (size_t)c * 8);
  }
  {
    int c = tid;
    int row = c >> 2;
    int sk = ((c & 3) ^ ((row >> 1) & 3)) * 8;
    GLD16(B + (size_t)(bn + row) * K + k0 + sk, Bs + (size_t)c * 8);
  }
}

__global__ __launch_bounds__(512, 3) void gemm_qkv256(
    const ushort* __restrict__ A, const ushort* __restrict__ B,
    ushort* __restrict__ C, int N, int K, int GX) {
  __shared__ ushort smem[2 * QTILE];   // 48 KB
  const int tid  = threadIdx.x;
  const int wave = tid >> 6;
  const int lane = tid & 63;
  const int nwg = gridDim.x;
  const int wg = (blockIdx.x & 7) * (nwg >> 3) + (blockIdx.x >> 3);
  const int bm = (wg / GX) * QBM;
  const int bn = (wg % GX) * QBN;
  const int wr = (wave >> 1) * 64;
  const int wc = (wave & 1) * 64;
  const int lm = lane & 15;
  const int g4 = lane >> 4;

  f32x4 acc[4][4];
#pragma unroll
  for (int m = 0; m < 4; ++m)
#pragma unroll
    for (int n = 0; n < 4; ++n) acc[m][n] = (f32x4){0.f, 0.f, 0.f, 0.f};

  const int ko = (g4 ^ ((lm >> 1) & 3)) * 8;

  const int nt = K / QBK;   // 16
  stage_q256(A, B, smem, smem + QBM * QBK, bm, bn, K, 0, tid);
  __syncthreads();

  int cur = 0;
  for (int t = 0; t < nt; ++t) {
    if (t + 1 < nt) {
      ushort* nb = smem + (cur ^ 1) * QTILE;
      stage_q256(A, B, nb, nb + QBM * QBK, bm, bn, K, (t + 1) * QBK, tid);
    }
    const ushort* As = smem + cur * QTILE;
    const ushort* Bs = As + QBM * QBK;
    short8 av[4], bv[4];
#pragma unroll
    for (int m = 0; m < 4; ++m)
      av[m] = *(const short8*)&As[(wr + m * 16 + lm) * QBK + ko];
#pragma unroll
    for (int n = 0; n < 4; ++n)
      bv[n] = *(const short8*)&Bs[(wc + n * 16 + lm) * QBK + ko];
#pragma unroll
    for (int m = 0; m < 4; ++m)
#pragma unroll
      for (int n = 0; n < 4; ++n)
        acc[m][n] = __builtin_amdgcn_mfma_f32_16x16x32_bf16(av[m], bv[n], acc[m][n], 0, 0, 0);
    __syncthreads();
    cur ^= 1;
  }

  // ---- epilogue: two 128-row passes through LDS (stride 136), bf16 out ----
  ushort* Cs = smem;
  const int cr = g4 * 4;
  const int cc = lm;
#pragma unroll
  for (int h = 0; h < 2; ++h) {
    __syncthreads();
    if ((wave >> 2) == h) {
      const int rb = ((wave >> 1) & 1) * 64;
#pragma unroll
      for (int m = 0; m < 4; ++m)
#pragma unroll
        for (int n = 0; n < 4; ++n)
#pragma unroll
          for (int r = 0; r < 4; ++r)
            Cs[(rb + m * 16 + cr + r) * 136 + wc + n * 16 + cc] = f2bf(acc[m][n][r]);
    }
    __syncthreads();
#pragma unroll
    for (int i = 0; i < 4; ++i) {
      int idx = i * 512 + tid;
      int row = idx >> 4, ch = idx & 15;
      uint4 v = *(const uint4*)&Cs[row * 136 + ch * 8];
      *(uint4*)(C + (size_t)(bm + h * 128 + row) * N + bn + ch * 8) = v;
    }
  }
}

// ---------------------------------------------------------------------------
// K1b: 128x128x32 GEMM (fp32 out) for the output projection — unchanged R5.
// ---------------------------------------------------------------------------
#define TBM 128
#define TBN 128
#define TBK 32
#define TILE_U ((TBM + TBN) * TBK)

static __device__ __forceinline__ void stage_tile(
    const ushort* __restrict__ A, const ushort* __restrict__ B,
    ushort* As, ushort* Bs, int bm, int bn, int K, int k0, int tid) {
#pragma unroll
  for (int it = 0; it < 2; ++it) {
    int c = it * 256 + tid;
    int row = c >> 2;
    int sk = ((c & 3) ^ ((row >> 1) & 3)) * 8;
    GLD16(A + (size_t)(bm + row) * K + k0 + sk, As + (size_t)c * 8);
    GLD16(B + (size_t)(bn + row) * K + k0 + sk, Bs + (size_t)c * 8);
  }
}

__global__ __launch_bounds__(256) void gemm_out_f32(
    const ushort* __restrict__ A, const ushort* __restrict__ B,
    float* __restrict__ C, int N, int K, int GX) {
  __shared__ ushort smem[3 * TILE_U];   // 48 KB
  const int tid  = threadIdx.x;
  const int wave = tid >> 6;
  const int lane = tid & 63;
  const int nwg = gridDim.x;
  const int wg = (blockIdx.x & 7) * (nwg >> 3) + (blockIdx.x >> 3);
  const int bm = (wg / GX) * TBM;
  const int bn = (wg % GX) * TBN;
  const int wr = (wave >> 1) * 64;
  const int wc = (wave & 1) * 64;
  const int lm = lane & 15;
  const int g4 = lane >> 4;

  f32x4 acc[4][4];
#pragma unroll
  for (int m = 0; m < 4; ++m)
#pragma unroll
    for (int n = 0; n < 4; ++n) acc[m][n] = (f32x4){0.f, 0.f, 0.f, 0.f};

  const int ko = (g4 ^ ((lm >> 1) & 3)) * 8;

  const int nt = K / TBK;   // 16
  stage_tile(A, B, smem, smem + TBM * TBK, bm, bn, K, 0, tid);
  {
    ushort* b1 = smem + TILE_U;
    stage_tile(A, B, b1, b1 + TBM * TBK, bm, bn, K, TBK, tid);
  }
  asm volatile("s_waitcnt vmcnt(4)" ::: "memory");
  __builtin_amdgcn_s_barrier();
  asm volatile("" ::: "memory");

  for (int t = 0; t < nt; ++t) {
    if (t + 2 < nt) {
      ushort* bn3 = smem + ((t + 2) % 3) * TILE_U;
      stage_tile(A, B, bn3, bn3 + TBM * TBK, bm, bn, K, (t + 2) * TBK, tid);
    }
    const ushort* As = smem + (t % 3) * TILE_U;
    const ushort* Bs = As + TBM * TBK;
    short8 av[4], bv[4];
#pragma unroll
    for (int m = 0; m < 4; ++m)
      av[m] = *(const short8*)&As[(wr + m * 16 + lm) * TBK + ko];
#pragma unroll
    for (int n = 0; n < 4; ++n)
      bv[n] = *(const short8*)&Bs[(wc + n * 16 + lm) * TBK + ko];
#pragma unroll
    for (int m = 0; m < 4; ++m)
#pragma unroll
      for (int n = 0; n < 4; ++n)
        acc[m][n] = __builtin_amdgcn_mfma_f32_16x16x32_bf16(av[m], bv[n], acc[m][n], 0, 0, 0);
    if (t + 1 < nt) {
      if (t + 2 < nt) asm volatile("s_waitcnt vmcnt(4)" ::: "memory");
      else            asm volatile("s_waitcnt vmcnt(0)" ::: "memory");
      __builtin_amdgcn_s_barrier();
      asm volatile("" ::: "memory");
    }
  }
  __syncthreads();

  const int cr = g4 * 4;
  const int cc = lm;
  float* Csf = (float*)smem;
#pragma unroll
  for (int s = 0; s < 4; ++s) {
    __syncthreads();
    if ((wave >> 1) == (s >> 1)) {
#pragma unroll
      for (int mi = 0; mi < 2; ++mi)
#pragma unroll
        for (int n = 0; n < 4; ++n)
#pragma unroll
          for (int r = 0; r < 4; ++r) {
            int m = (s & 1) * 2 + mi;
            Csf[(mi * 16 + cr + r) * 128 + wc + n * 16 + cc] = acc[m][n][r];
          }
    }
    __syncthreads();
#pragma unroll
    for (int i = 0; i < 4; ++i) {
      int idx = i * 256 + tid;
      int row = idx >> 5, ch = idx & 31;
      float4 v = *(const float4*)&Csf[row * 128 + ch * 4];
      *(float4*)(C + (size_t)(bm + s * 32 + row) * N + bn + ch * 4) = v;
    }
  }
}

// ---------------------------------------------------------------------------
// K3: MFMA neighborhood attention + fused RMSNorm/RoPE — R7 structure
// RESTORED (48 KB LDS, full Vt, 5 barriers; R8's split-Vt cost +1.9 us with
// no occupancy gain). Riders: exp2f with log2e folded into scale; T5
// s_setprio(1) around the St and PV MFMA clusters (m191: attn-positive).
// ---------------------------------------------------------------------------
__global__ __launch_bounds__(256) void attn_kernel(
    const ushort* __restrict__ qkv, ushort* __restrict__ outb,
    const float* __restrict__ csn, const float* __restrict__ qg,
    const float* __restrict__ kg) {
  __shared__ ushort lds[24576];          // 48 KB
  ushort* K_s  = lds;                    // [192 k][64 d], chunk swz c^(kr&7)
  ushort* Vt_s = lds + 12288;            // [64 d][192 k], swizzled chunks
  ushort* P_s  = lds;                    // [64 q][192 k] aliases K_s
  ushort* O_s  = lds + 12288;            // [64 q][68 d-stride] aliases Vt_s

  const int tid = threadIdx.x;
  const int wave = tid >> 6;
  const int lane = tid & 63;
  const int lin = blockIdx.x;
  const int bid = (lin & 7) * 256 + (lin >> 3);   // XCD-chunked (2048 % 8 == 0)
  const int tw = bid & 7, th = (bid >> 3) & 15, n = (bid >> 7) & 7, b = bid >> 10;
  const int hb = th * 2, wb = tw * 4;
  const int hb0 = max(hb - 1, 0), wb0 = max(wb - 1, 0);
  const int lm = lane & 15, g4 = lane >> 4;

  // ---- V + K: reg-stage 6 chunks/thread each ----
  float4 vreg[6], kreg[6];
  int mi6[6];
#pragma unroll
  for (int it = 0; it < 6; ++it) {
    int c = it * 256 + tid;
    int kr = c >> 3, gv = c & 7;
    int sc = kr >> 3, t = kr & 7;
    int kh = sc / 6, kw = sc - kh * 6;
    int hh = min(hb0 + kh, 31), ww = min(wb0 + kw, 31);
    size_t m = (((size_t)(b * 8 + t) * 32 + hh) * 32 + ww);
    mi6[it] = (int)(m & 8191);
    const ushort* bp = qkv + m * C3 + n * 192;
    vreg[it] = *(const float4*)(bp + 128 + gv * 8);
    kreg[it] = *(const float4*)(bp + 64 + gv * 8);
  }

  // ---- Q: wave's 16-q fragment, fused norm + rope in-register ----
  short8 bq[2];
  {
    int q = wave * 16 + lm;
    int tq = q >> 3, p = q & 7;
    size_t mq = (((size_t)(b * 8 + tq) * 32 + (hb + (p >> 2))) * 32 + (wb + (p & 3)));
    const ushort* qp = qkv + mq * C3 + n * 192;
    union { short8 s; ushort u[8]; } Lq0, Lq1;
    Lq0.s = *(const short8*)(qp + g4 * 8);
    Lq1.s = *(const short8*)(qp + (4 + g4) * 8);
    float fq[16];
    float ssq = 0.f;
#pragma unroll
    for (int j = 0; j < 8; ++j) { fq[j] = bf2f(Lq0.u[j]); ssq += fq[j] * fq[j]; }
#pragma unroll
    for (int j = 0; j < 8; ++j) { fq[8 + j] = bf2f(Lq1.u[j]); ssq += fq[8 + j] * fq[8 + j]; }
    ssq += __shfl_xor(ssq, 16);
    ssq += __shfl_xor(ssq, 32);
    const float rq = rsqrtf(ssq * (1.f / 64.f) + 1e-6f);
    const int miq = (int)(mq & 8191);
#pragma unroll
    for (int kk = 0; kk < 2; ++kk) {
      const int ch0 = (kk * 4 + g4) * 8;
      const float4 ga = *(const float4*)(qg + ch0);
      const float4 gb = *(const float4*)(qg + ch0 + 4);
      const float* cbp = csn + (size_t)miq * 64 + ch0;
      const float4 c0 = *(const float4*)cbp;
      const float4 c1 = *(const float4*)(cbp + 4);
      const float* fv = &fq[kk * 8];
      union { short8 s; ushort u[8]; } O;
      float xe, xo;
      xe = fv[0] * rq * ga.x; xo = fv[1] * rq * ga.y;
      O.u[0] = f2bf(xe * c0.x - xo * c0.y); O.u[1] = f2bf(xe * c0.y + xo * c0.x);
      xe = fv[2] * rq * ga.z; xo = fv[3] * rq * ga.w;
      O.u[2] = f2bf(xe * c0.z - xo * c0.w); O.u[3] = f2bf(xe * c0.w + xo * c0.z);
      xe = fv[4] * rq * gb.x; xo = fv[5] * rq * gb.y;
      O.u[4] = f2bf(xe * c1.x - xo * c1.y); O.u[5] = f2bf(xe * c1.y + xo * c1.x);
      xe = fv[6] * rq * gb.z; xo = fv[7] * rq * gb.w;
      O.u[6] = f2bf(xe * c1.z - xo * c1.w); O.u[7] = f2bf(xe * c1.w + xo * c1.z);
      bq[kk] = O.s;
    }
  }

  // ---- K: fused norm + rope, swizzled ds_write_b128 into K_s ----
#pragma unroll
  for (int it = 0; it < 6; ++it) {
    int c = it * 256 + tid;
    int kr = c >> 3, g = c & 7;
    union { float4 f; ushort u[8]; } L;
    L.f = kreg[it];
    float f0 = bf2f(L.u[0]), f1 = bf2f(L.u[1]), f2 = bf2f(L.u[2]), f3 = bf2f(L.u[3]);
    float f4 = bf2f(L.u[4]), f5 = bf2f(L.u[5]), f6 = bf2f(L.u[6]), f7 = bf2f(L.u[7]);
    float ss = f0 * f0 + f1 * f1 + f2 * f2 + f3 * f3 +
               f4 * f4 + f5 * f5 + f6 * f6 + f7 * f7;
    ss += __shfl_xor(ss, 1);
    ss += __shfl_xor(ss, 2);
    ss += __shfl_xor(ss, 4);
    const float rn = rsqrtf(ss * (1.f / 64.f) + 1e-6f);
    const float4 ga = *(const float4*)(kg + g * 8);
    const float4 gb = *(const float4*)(kg + g * 8 + 4);
    const float* cbp = csn + (size_t)mi6[it] * 64 + g * 8;
    const float4 c0 = *(const float4*)cbp;
    const float4 c1 = *(const float4*)(cbp + 4);
    union { short8 s; ushort u[8]; } O;
    float xe, xo;
    xe = f0 * rn * ga.x; xo = f1 * rn * ga.y;
    O.u[0] = f2bf(xe * c0.x - xo * c0.y); O.u[1] = f2bf(xe * c0.y + xo * c0.x);
    xe = f2 * rn * ga.z; xo = f3 * rn * ga.w;
    O.u[2] = f2bf(xe * c0.z - xo * c0.w); O.u[3] = f2bf(xe * c0.w + xo * c0.z);
    xe = f4 * rn * gb.x; xo = f5 * rn * gb.y;
    O.u[4] = f2bf(xe * c1.x - xo * c1.y); O.u[5] = f2bf(xe * c1.y + xo * c1.x);
    xe = f6 * rn * gb.z; xo = f7 * rn * gb.w;
    O.u[6] = f2bf(xe * c1.z - xo * c1.w); O.u[7] = f2bf(xe * c1.w + xo * c1.z);
    *(short8*)&K_s[kr * 64 + ((g ^ (kr & 7)) * 8)] = O.s;
  }

  __syncthreads();  // bar1: K staged (normed+roped)

  // ---- Vt transposed scatter-write (overlaps St on LDS pipe) ----
#pragma unroll
  for (int it = 0; it < 6; ++it) {
    int c = it * 256 + tid;
    int kr = c >> 3, gv = c & 7;
    int ck = kr >> 3, kin = kr & 7;
    union { float4 f; ushort u[8]; } vv;
    vv.f = vreg[it];
#pragma unroll
    for (int j = 0; j < 8; ++j) {
      int d = gv * 8 + j;
      int cks = ck ^ ((j ^ gv) & 7);       // group-preserving low-3 XOR
      Vt_s[d * 192 + cks * 8 + kin] = vv.u[j];
    }
  }

  // ---- St = K·Q^T : wave computes ONLY its 16 q (no redundancy) ----
  f32x4 st[12];
#pragma unroll
  for (int kf = 0; kf < 12; ++kf) st[kf] = (f32x4){0.f, 0.f, 0.f, 0.f};
  __builtin_amdgcn_s_setprio(1);
#pragma unroll
  for (int kk = 0; kk < 2; ++kk)
#pragma unroll
    for (int kf = 0; kf < 12; ++kf) {
      int kr = kf * 16 + lm;
      short8 a = *(const short8*)&K_s[kr * 64 + (((kk * 4 + g4) ^ (kr & 7)) * 8)];
      st[kf] = __builtin_amdgcn_mfma_f32_16x16x32_bf16(a, bq[kk], st[kf], 0, 0, 0);
    }
  __builtin_amdgcn_s_setprio(0);

  // ---- mask + softmax (exp2, log2e folded into scale) ----
  const int p = lm & 7;
  const int qh = hb + (p >> 2), qw = wb + (p & 3);
  const int loh = min(max(qh - 1, 0), 29), low = min(max(qw - 1, 0), 29);
  uint mk = 0;
#pragma unroll
  for (int kf = 0; kf < 12; ++kf) {
    int sc = kf * 2 + (g4 >> 1);
    int kh = sc / 6, kw = sc - kh * 6;
    int khg = hb0 + kh, kwg = wb0 + kw;
    bool ok = (khg >= loh) && (khg <= loh + 2) && (kwg >= low) && (kwg <= low + 2);
    mk |= (uint)ok << kf;
  }
  const float scale = 0.125f * 1.44269504088896f;   // /8, x log2(e)
#pragma unroll
  for (int kf = 0; kf < 12; ++kf) {
    bool ok = (mk >> kf) & 1;
#pragma unroll
    for (int r = 0; r < 4; ++r)
      st[kf][r] = ok ? st[kf][r] * scale : -1e30f;
  }
  float mx = -1e30f;
#pragma unroll
  for (int kf = 0; kf < 12; ++kf)
#pragma unroll
    for (int r = 0; r < 4; ++r) mx = fmaxf(mx, st[kf][r]);
  mx = fmaxf(mx, __shfl_xor(mx, 16));
  mx = fmaxf(mx, __shfl_xor(mx, 32));
  float s = 0.f;
#pragma unroll
  for (int kf = 0; kf < 12; ++kf)
#pragma unroll
    for (int r = 0; r < 4; ++r) {
      float e = exp2f(st[kf][r] - mx);
      st[kf][r] = e;
      s += e;
    }
  s += __shfl_xor(s, 16);
  s += __shfl_xor(s, 32);
  const float inv = 1.f / s;
  __syncthreads();  // bar2: K reads done (P may overwrite), Vt writes visible

  // ---- P write: wave-disjoint rows q = wave*16+lm ----
  {
    const int q = wave * 16 + lm;
    ushort* Prow = P_s + q * 192 + (g4 & 1) * 4;
#pragma unroll
    for (int kf = 0; kf < 12; ++kf) {
      uint lo = (uint)f2bf(st[kf][0] * inv) | ((uint)f2bf(st[kf][1] * inv) << 16);
      uint hi = (uint)f2bf(st[kf][2] * inv) | ((uint)f2bf(st[kf][3] * inv) << 16);
      int ck = kf * 2 + (g4 >> 1);
      int cks = ck ^ (lm & 7);
      uint2 val; val.x = lo; val.y = hi;
      *(uint2*)(Prow + cks * 8) = val;
    }
  }
  __syncthreads();  // bar3: P ready

  // ---- PV: wave owns d-block wave*16; out[q][d] for all 4 q-frags ----
  f32x4 ao0 = (f32x4){0.f, 0.f, 0.f, 0.f};
  f32x4 ao1 = (f32x4){0.f, 0.f, 0.f, 0.f};
  f32x4 ao2 = (f32x4){0.f, 0.f, 0.f, 0.f};
  f32x4 ao3 = (f32x4){0.f, 0.f, 0.f, 0.f};
  const int drow = wave * 16 + lm;
  const int dsw = (lm & 7) ^ ((wave * 2 + (lm >> 3)) & 7);
  __builtin_amdgcn_s_setprio(1);
#pragma unroll
  for (int kk = 0; kk < 6; ++kk) {
    int ch = kk * 4 + g4;
    short8 bv = *(const short8*)&Vt_s[drow * 192 + ((ch ^ dsw) * 8)];
    int pch = (ch ^ (lm & 7)) * 8;
    short8 av0 = *(const short8*)&P_s[(0 * 16 + lm) * 192 + pch];
    short8 av1 = *(const short8*)&P_s[(1 * 16 + lm) * 192 + pch];
    short8 av2 = *(const short8*)&P_s[(2 * 16 + lm) * 192 + pch];
    short8 av3 = *(const short8*)&P_s[(3 * 16 + lm) * 192 + pch];
    ao0 = __builtin_amdgcn_mfma_f32_16x16x32_bf16(av0, bv, ao0, 0, 0, 0);
    ao1 = __builtin_amdgcn_mfma_f32_16x16x32_bf16(av1, bv, ao1, 0, 0, 0);
    ao2 = __builtin_amdgcn_mfma_f32_16x16x32_bf16(av2, bv, ao2, 0, 0, 0);
    ao3 = __builtin_amdgcn_mfma_f32_16x16x32_bf16(av3, bv, ao3, 0, 0, 0);
  }
  __builtin_amdgcn_s_setprio(0);
  __syncthreads();  // bar4: PV's Vt/P reads done; O may overwrite Vt region

  // ---- epilogue: O via LDS (stride 68), coalesced bf16 store ----
#pragma unroll
  for (int r = 0; r < 4; ++r) {
    O_s[(0 * 16 + g4 * 4 + r) * 68 + (wave * 16 + lm)] = f2bf(ao0[r]);
    O_s[(1 * 16 + g4 * 4 + r) * 68 + (wave * 16 + lm)] = f2bf(ao1[r]);
    O_s[(2 * 16 + g4 * 4 + r) * 68 + (wave * 16 + lm)] = f2bf(ao2[r]);
    O_s[(3 * 16 + g4 * 4 + r) * 68 + (wave * 16 + lm)] = f2bf(ao3[r]);
  }
  __syncthreads();  // bar5
#pragma unroll
  for (int i = 0; i < 2; ++i) {
    int idx = i * 256 + tid;
    int q = idx >> 3, c = idx & 7;
    short8 v = *(const short8*)&O_s[q * 68 + c * 8];
    int tq = q >> 3, pp = q & 7;
    size_t m = (((size_t)(b * 8 + tq) * 32 + (hb + (pp >> 2))) * 32 + (wb + (pp & 3)));
    *(short8*)(outb + m * (size_t)C_ + n * 64 + c * 8) = v;
  }
}

// ---------------------------------------------------------------------------
extern "C" void kernel_launch(void* const* d_in, const int* in_sizes, int n_in,
                              void* d_out, int out_size, void* d_ws, size_t ws_size,
                              hipStream_t stream) {
  const float* x     = (const float*)d_in[0];
  const float* freqs = (const float*)d_in[1];
  const float* w_in  = (const float*)d_in[2];
  const float* w_out = (const float*)d_in[3];
  const float* qg    = (const float*)d_in[4];
  const float* kg    = (const float*)d_in[5];
  float* out = (float*)d_out;

  char* ws = (char*)d_ws;
  ushort* qkv   = (ushort*)ws;                                    // 50.3 MB bf16
  ushort* xb    = (ushort*)(ws + (size_t)NTOK * C3 * 2);          // 16.8 MB
  ushort* wib   = xb + (size_t)NTOK * C_;                         // 1.5 MB
  ushort* wob   = wib + (size_t)C3 * C_;                          // 0.5 MB
  ushort* attnb = wob + (size_t)C_ * C_;                          // 16.8 MB
  // cos/sin table lives in d_out scratch (2 MB): written by cast3, read by
  // attn, then fully overwritten by gemm2's fp32 output. Stream-ordered.
  float* csn = out;

  // 0) fused casts + sincos table (128 extra blocks)
  cast3_kernel<<<4736, 256, 0, stream>>>(x, w_in, w_out, freqs, xb, wib, wob,
                                         (float2*)csn);

  // 1) qkv = x @ w_in^T (bf16 out). 256x128 tile, grid 768 = 3 blocks/CU.
  gemm_qkv256<<<768, 512, 0, stream>>>(xb, wib, qkv, C3, C_, 12);
  // 2) MFMA neighborhood attention with fused RMSNorm+RoPE -> attnb.
  //    48 KB LDS (R7 structure). grid 2048 = 2b x 8n x 16th x 8tw.
  attn_kernel<<<2048, 256, 0, stream>>>(qkv, attnb, csn, qg, kg);
  // 3) out = attn @ w_out^T (fp32 out). grid 512 = 128 bm x 4 bn.
  gemm_out_f32<<<512, 256, 0, stream>>>(attnb, wob, out, C_, C_, 4);
}

// Round 10
// 99.811 us; speedup vs baseline: 1.0320x; 1.0320x over previous
//
#include <hip/hip_runtime.h>
#include <hip/hip_bf16.h>
#include <math.h>

#define NH 8
#define C_ 512
#define C3 1536
#define NTOK 16384   // b*t*h*w = 2*8*32*32

typedef __attribute__((ext_vector_type(8))) short short8;
typedef __attribute__((ext_vector_type(4))) float f32x4;
typedef __attribute__((address_space(3))) void* lds_ptr_t;
typedef const __attribute__((address_space(1))) void* gbl_ptr_t;

static __device__ __forceinline__ ushort f2bf(float f) {
  __hip_bfloat16 h = __float2bfloat16(f);
  return *reinterpret_cast<ushort*>(&h);
}
static __device__ __forceinline__ float bf2f(ushort u) {
  uint t = ((uint)u) << 16;
  float f;
  __builtin_memcpy(&f, &t, 4);
  return f;
}

// ---------------------------------------------------------------------------
// K0: fused fp32 -> bf16 cast for x, w_in, w_out PLUS cos/sin table for rope.
// csn[idx] = (cosf(freqs[idx]), sinf(freqs[idx])), idx over 8*32*32*32 = 262144.
// Table lives in d_out scratch (overwritten later by gemm2; stream-ordered).
// ---------------------------------------------------------------------------
__global__ __launch_bounds__(256) void cast3_kernel(
    const float* __restrict__ x, const float* __restrict__ wi,
    const float* __restrict__ wo, const float* __restrict__ fr,
    ushort* __restrict__ xb, ushort* __restrict__ wib,
    ushort* __restrict__ wob, float2* __restrict__ csn) {
  const int blk = blockIdx.x;
  if (blk >= 4608) {   // 128 blocks: sincos table (8 entries/thread)
    int i = (blk - 4608) * 256 + threadIdx.x;
    const float4* fp = (const float4*)fr + (size_t)i * 2;
    float4 a = fp[0], b = fp[1];
    float v[8] = {a.x, a.y, a.z, a.w, b.x, b.y, b.z, b.w};
    float2 o[8];
#pragma unroll
    for (int j = 0; j < 8; ++j) { o[j].x = cosf(v[j]); o[j].y = sinf(v[j]); }
    float4* op = (float4*)(csn + (size_t)i * 8);
    op[0] = make_float4(o[0].x, o[0].y, o[1].x, o[1].y);
    op[1] = make_float4(o[2].x, o[2].y, o[3].x, o[3].y);
    op[2] = make_float4(o[4].x, o[4].y, o[5].x, o[5].y);
    op[3] = make_float4(o[6].x, o[6].y, o[7].x, o[7].y);
    return;
  }
  const float* src;
  ushort* dst;
  int i;
  if (blk < 4096)      { src = x;  dst = xb;  i = blk * 256 + threadIdx.x; }
  else if (blk < 4480) { src = wi; dst = wib; i = (blk - 4096) * 256 + threadIdx.x; }
  else                 { src = wo; dst = wob; i = (blk - 4480) * 256 + threadIdx.x; }
  const float4* p = (const float4*)src + (size_t)i * 2;
  float4 v0 = p[0], v1 = p[1];
  union { ushort u[8]; uint4 v; } r;
  r.u[0] = f2bf(v0.x); r.u[1] = f2bf(v0.y); r.u[2] = f2bf(v0.z); r.u[3] = f2bf(v0.w);
  r.u[4] = f2bf(v1.x); r.u[5] = f2bf(v1.y); r.u[6] = f2bf(v1.z); r.u[7] = f2bf(v1.w);
  *(uint4*)(dst + (size_t)i * 8) = r.v;
}

// ---------------------------------------------------------------------------
// bf16 NT GEMM via MFMA: 128x128x32 tile, 3-buffer LDS / 2-deep prefetch and
// counted vmcnt. Steady state: issue stage(t+2), compute buf[t%3], wait
// vmcnt(4), raw s_barrier + compiler fence. LDS 48 KB -> 3 blocks/CU.
// T2 source swizzle + T1 XCD swizzle.
// ---------------------------------------------------------------------------
#define TBM 128
#define TBN 128
#define TBK 32
#define TILE_U ((TBM + TBN) * TBK)

static __device__ __forceinline__ void stage_tile(
    const ushort* __restrict__ A, const ushort* __restrict__ B,
    ushort* As, ushort* Bs, int bm, int bn, int K, int k0, int tid) {
#pragma unroll
  for (int it = 0; it < 2; ++it) {
    int c = it * 256 + tid;
    int row = c >> 2;
    int sk = ((c & 3) ^ ((row >> 1) & 3)) * 8;
    __builtin_amdgcn_global_load_lds(
        (gbl_ptr_t)(const void*)(A + (size_t)(bm + row) * K + k0 + sk),
        (lds_ptr_t)(As + (size_t)c * 8), 16, 0, 0);
    __builtin_amdgcn_global_load_lds(
        (gbl_ptr_t)(const void*)(B + (size_t)(bn + row) * K + k0 + sk),
        (lds_ptr_t)(Bs + (size_t)c * 8), 16, 0, 0);
  }
}

template <bool BF16OUT>
__global__ __launch_bounds__(256) void gemm_bt_bf16(
    const ushort* __restrict__ A, const ushort* __restrict__ B,
    void* __restrict__ Cv, int N, int K, int GX) {
  __shared__ ushort smem[3 * TILE_U];   // 48 KB
  const int tid  = threadIdx.x;
  const int wave = tid >> 6;
  const int lane = tid & 63;
  const int nwg = gridDim.x;
  const int wg = (blockIdx.x & 7) * (nwg >> 3) + (blockIdx.x >> 3);
  const int bm = (wg / GX) * TBM;
  const int bn = (wg % GX) * TBN;
  const int wr = (wave >> 1) * 64;
  const int wc = (wave & 1) * 64;
  const int lm = lane & 15;
  const int g4 = lane >> 4;

  f32x4 acc[4][4];
#pragma unroll
  for (int m = 0; m < 4; ++m)
#pragma unroll
    for (int n = 0; n < 4; ++n) acc[m][n] = (f32x4){0.f, 0.f, 0.f, 0.f};

  const int ko = (g4 ^ ((lm >> 1) & 3)) * 8;

  const int nt = K / TBK;   // 16
  // prologue: 2-deep prefetch (tiles 0,1 -> buf 0,1); wait tile0 only.
  stage_tile(A, B, smem, smem + TBM * TBK, bm, bn, K, 0, tid);
  {
    ushort* b1 = smem + TILE_U;
    stage_tile(A, B, b1, b1 + TBM * TBK, bm, bn, K, TBK, tid);
  }
  asm volatile("s_waitcnt vmcnt(4)" ::: "memory");
  __builtin_amdgcn_s_barrier();
  asm volatile("" ::: "memory");

  for (int t = 0; t < nt; ++t) {
    if (t + 2 < nt) {
      ushort* bn3 = smem + ((t + 2) % 3) * TILE_U;
      stage_tile(A, B, bn3, bn3 + TBM * TBK, bm, bn, K, (t + 2) * TBK, tid);
    }
    const ushort* As = smem + (t % 3) * TILE_U;
    const ushort* Bs = As + TBM * TBK;
    short8 av[4], bv[4];
#pragma unroll
    for (int m = 0; m < 4; ++m)
      av[m] = *(const short8*)&As[(wr + m * 16 + lm) * TBK + ko];
#pragma unroll
    for (int n = 0; n < 4; ++n)
      bv[n] = *(const short8*)&Bs[(wc + n * 16 + lm) * TBK + ko];
#pragma unroll
    for (int m = 0; m < 4; ++m)
#pragma unroll
      for (int n = 0; n < 4; ++n)
        acc[m][n] = __builtin_amdgcn_mfma_f32_16x16x32_bf16(av[m], bv[n], acc[m][n], 0, 0, 0);
    if (t + 1 < nt) {
      if (t + 2 < nt) asm volatile("s_waitcnt vmcnt(4)" ::: "memory");
      else            asm volatile("s_waitcnt vmcnt(0)" ::: "memory");
      __builtin_amdgcn_s_barrier();
      asm volatile("" ::: "memory");
    }
  }
  __syncthreads();   // all waves done computing; LDS reusable for epilogue

  const int cr = g4 * 4;
  const int cc = lm;

  if (BF16OUT) {
    ushort* Cs = smem;
    ushort* C = (ushort*)Cv;
#pragma unroll
    for (int h = 0; h < 2; ++h) {
      __syncthreads();
      if ((wave >> 1) == h) {
#pragma unroll
        for (int m = 0; m < 4; ++m)
#pragma unroll
          for (int n = 0; n < 4; ++n)
#pragma unroll
            for (int r = 0; r < 4; ++r)
              Cs[(m * 16 + cr + r) * 128 + wc + n * 16 + cc] = f2bf(acc[m][n][r]);
      }
      __syncthreads();
#pragma unroll
      for (int i = 0; i < 4; ++i) {
        int idx = i * 256 + tid;
        int row = idx >> 4, ch = idx & 15;
        uint4 v = *(const uint4*)&Cs[row * 128 + ch * 8];
        *(uint4*)(C + (size_t)(bm + h * 64 + row) * N + bn + ch * 8) = v;
      }
    }
  } else {
    float* Csf = (float*)smem;
    float* C = (float*)Cv;
#pragma unroll
    for (int s = 0; s < 4; ++s) {
      __syncthreads();
      if ((wave >> 1) == (s >> 1)) {
#pragma unroll
        for (int mi = 0; mi < 2; ++mi)
#pragma unroll
          for (int n = 0; n < 4; ++n)
#pragma unroll
            for (int r = 0; r < 4; ++r) {
              int m = (s & 1) * 2 + mi;
              Csf[(mi * 16 + cr + r) * 128 + wc + n * 16 + cc] = acc[m][n][r];
            }
      }
      __syncthreads();
#pragma unroll
      for (int i = 0; i < 4; ++i) {
        int idx = i * 256 + tid;
        int row = idx >> 5, ch = idx & 31;
        float4 v = *(const float4*)&Csf[row * 128 + ch * 4];
        *(float4*)(C + (size_t)(bm + s * 32 + row) * N + bn + ch * 4) = v;
      }
    }
  }
}

// ---------------------------------------------------------------------------
// K3: MFMA neighborhood attention with FUSED RMSNorm + RoPE on q and k.
// (R4 structure — measured-best attn: 48 KB, full Vt, __expf, no setprio)
// ---------------------------------------------------------------------------
__global__ __launch_bounds__(256) void attn_kernel(
    const ushort* __restrict__ qkv, ushort* __restrict__ outb,
    const float* __restrict__ csn, const float* __restrict__ qg,
    const float* __restrict__ kg) {
  __shared__ ushort lds[24576];          // 48 KB
  ushort* K_s  = lds;                    // [192 k][64 d], chunk swz c^(kr&7)
  ushort* Vt_s = lds + 12288;            // [64 d][192 k], swizzled chunks
  ushort* P_s  = lds;                    // [64 q][192 k] aliases K_s
  ushort* O_s  = lds + 12288;            // [64 q][68 d-stride] aliases Vt_s

  const int tid = threadIdx.x;
  const int wave = tid >> 6;
  const int lane = tid & 63;
  const int lin = blockIdx.x;
  const int bid = (lin & 7) * 256 + (lin >> 3);   // XCD-chunked (2048 % 8 == 0)
  const int tw = bid & 7, th = (bid >> 3) & 15, n = (bid >> 7) & 7, b = bid >> 10;
  const int hb = th * 2, wb = tw * 4;
  const int hb0 = max(hb - 1, 0), wb0 = max(wb - 1, 0);
  const int lm = lane & 15, g4 = lane >> 4;

  // ---- V + K: reg-stage 6 chunks/thread each ----
  float4 vreg[6], kreg[6];
  int mi6[6];
#pragma unroll
  for (int it = 0; it < 6; ++it) {
    int c = it * 256 + tid;
    int kr = c >> 3, gv = c & 7;
    int sc = kr >> 3, t = kr & 7;
    int kh = sc / 6, kw = sc - kh * 6;
    int hh = min(hb0 + kh, 31), ww = min(wb0 + kw, 31);
    size_t m = (((size_t)(b * 8 + t) * 32 + hh) * 32 + ww);
    mi6[it] = (int)(m & 8191);
    const ushort* bp = qkv + m * C3 + n * 192;
    vreg[it] = *(const float4*)(bp + 128 + gv * 8);
    kreg[it] = *(const float4*)(bp + 64 + gv * 8);
  }

  // ---- Q: wave's 16-q fragment, fused norm + rope in-register ----
  short8 bq[2];
  {
    int q = wave * 16 + lm;
    int tq = q >> 3, p = q & 7;
    size_t mq = (((size_t)(b * 8 + tq) * 32 + (hb + (p >> 2))) * 32 + (wb + (p & 3)));
    const ushort* qp = qkv + mq * C3 + n * 192;
    union { short8 s; ushort u[8]; } Lq0, Lq1;
    Lq0.s = *(const short8*)(qp + g4 * 8);
    Lq1.s = *(const short8*)(qp + (4 + g4) * 8);
    float fq[16];
    float ssq = 0.f;
#pragma unroll
    for (int j = 0; j < 8; ++j) { fq[j] = bf2f(Lq0.u[j]); ssq += fq[j] * fq[j]; }
#pragma unroll
    for (int j = 0; j < 8; ++j) { fq[8 + j] = bf2f(Lq1.u[j]); ssq += fq[8 + j] * fq[8 + j]; }
    ssq += __shfl_xor(ssq, 16);
    ssq += __shfl_xor(ssq, 32);
    const float rq = rsqrtf(ssq * (1.f / 64.f) + 1e-6f);
    const int miq = (int)(mq & 8191);
#pragma unroll
    for (int kk = 0; kk < 2; ++kk) {
      const int ch0 = (kk * 4 + g4) * 8;
      const float4 ga = *(const float4*)(qg + ch0);
      const float4 gb = *(const float4*)(qg + ch0 + 4);
      const float* cbp = csn + (size_t)miq * 64 + ch0;
      const float4 c0 = *(const float4*)cbp;
      const float4 c1 = *(const float4*)(cbp + 4);
      const float* fv = &fq[kk * 8];
      union { short8 s; ushort u[8]; } O;
      float xe, xo;
      xe = fv[0] * rq * ga.x; xo = fv[1] * rq * ga.y;
      O.u[0] = f2bf(xe * c0.x - xo * c0.y); O.u[1] = f2bf(xe * c0.y + xo * c0.x);
      xe = fv[2] * rq * ga.z; xo = fv[3] * rq * ga.w;
      O.u[2] = f2bf(xe * c0.z - xo * c0.w); O.u[3] = f2bf(xe * c0.w + xo * c0.z);
      xe = fv[4] * rq * gb.x; xo = fv[5] * rq * gb.y;
      O.u[4] = f2bf(xe * c1.x - xo * c1.y); O.u[5] = f2bf(xe * c1.y + xo * c1.x);
      xe = fv[6] * rq * gb.z; xo = fv[7] * rq * gb.w;
      O.u[6] = f2bf(xe * c1.z - xo * c1.w); O.u[7] = f2bf(xe * c1.w + xo * c1.z);
      bq[kk] = O.s;
    }
  }

  // ---- K: fused norm + rope, then swizzled ds_write_b128 into K_s ----
#pragma unroll
  for (int it = 0; it < 6; ++it) {
    int c = it * 256 + tid;
    int kr = c >> 3, g = c & 7;
    union { float4 f; ushort u[8]; } L;
    L.f = kreg[it];
    float f0 = bf2f(L.u[0]), f1 = bf2f(L.u[1]), f2 = bf2f(L.u[2]), f3 = bf2f(L.u[3]);
    float f4 = bf2f(L.u[4]), f5 = bf2f(L.u[5]), f6 = bf2f(L.u[6]), f7 = bf2f(L.u[7]);
    float ss = f0 * f0 + f1 * f1 + f2 * f2 + f3 * f3 +
               f4 * f4 + f5 * f5 + f6 * f6 + f7 * f7;
    ss += __shfl_xor(ss, 1);
    ss += __shfl_xor(ss, 2);
    ss += __shfl_xor(ss, 4);
    const float rn = rsqrtf(ss * (1.f / 64.f) + 1e-6f);
    const float4 ga = *(const float4*)(kg + g * 8);
    const float4 gb = *(const float4*)(kg + g * 8 + 4);
    const float* cbp = csn + (size_t)mi6[it] * 64 + g * 8;
    const float4 c0 = *(const float4*)cbp;
    const float4 c1 = *(const float4*)(cbp + 4);
    union { short8 s; ushort u[8]; } O;
    float xe, xo;
    xe = f0 * rn * ga.x; xo = f1 * rn * ga.y;
    O.u[0] = f2bf(xe * c0.x - xo * c0.y); O.u[1] = f2bf(xe * c0.y + xo * c0.x);
    xe = f2 * rn * ga.z; xo = f3 * rn * ga.w;
    O.u[2] = f2bf(xe * c0.z - xo * c0.w); O.u[3] = f2bf(xe * c0.w + xo * c0.z);
    xe = f4 * rn * gb.x; xo = f5 * rn * gb.y;
    O.u[4] = f2bf(xe * c1.x - xo * c1.y); O.u[5] = f2bf(xe * c1.y + xo * c1.x);
    xe = f6 * rn * gb.z; xo = f7 * rn * gb.w;
    O.u[6] = f2bf(xe * c1.z - xo * c1.w); O.u[7] = f2bf(xe * c1.w + xo * c1.z);
    *(short8*)&K_s[kr * 64 + ((g ^ (kr & 7)) * 8)] = O.s;
  }

  __syncthreads();  // bar1: K staged (normed+roped)

  // ---- Vt transposed scatter-write (overlaps St on LDS pipe) ----
#pragma unroll
  for (int it = 0; it < 6; ++it) {
    int c = it * 256 + tid;
    int kr = c >> 3, gv = c & 7;
    int ck = kr >> 3, kin = kr & 7;
    union { float4 f; ushort u[8]; } vv;
    vv.f = vreg[it];
#pragma unroll
    for (int j = 0; j < 8; ++j) {
      int d = gv * 8 + j;
      int cks = ck ^ ((j ^ gv) & 7);       // group-preserving low-3 XOR
      Vt_s[d * 192 + cks * 8 + kin] = vv.u[j];
    }
  }

  // ---- St = K·Q^T : wave computes ONLY its 16 q (no redundancy) ----
  f32x4 st[12];
#pragma unroll
  for (int kf = 0; kf < 12; ++kf) st[kf] = (f32x4){0.f, 0.f, 0.f, 0.f};
#pragma unroll
  for (int kk = 0; kk < 2; ++kk)
#pragma unroll
    for (int kf = 0; kf < 12; ++kf) {
      int kr = kf * 16 + lm;
      short8 a = *(const short8*)&K_s[kr * 64 + (((kk * 4 + g4) ^ (kr & 7)) * 8)];
      st[kf] = __builtin_amdgcn_mfma_f32_16x16x32_bf16(a, bq[kk], st[kf], 0, 0, 0);
    }

  // ---- mask + softmax (lane: q-col = wave*16+lm; k = kf*16 + g4*4 + r) ----
  const int p = lm & 7;                   // (wave*16+lm)&7 == lm&7
  const int qh = hb + (p >> 2), qw = wb + (p & 3);
  const int loh = min(max(qh - 1, 0), 29), low = min(max(qw - 1, 0), 29);
  uint mk = 0;
#pragma unroll
  for (int kf = 0; kf < 12; ++kf) {
    int sc = kf * 2 + (g4 >> 1);
    int kh = sc / 6, kw = sc - kh * 6;
    int khg = hb0 + kh, kwg = wb0 + kw;   // nominal (unclamped) position
    bool ok = (khg >= loh) && (khg <= loh + 2) && (kwg >= low) && (kwg <= low + 2);
    mk |= (uint)ok << kf;
  }
  const float scale = 0.125f;
#pragma unroll
  for (int kf = 0; kf < 12; ++kf) {
    bool ok = (mk >> kf) & 1;
#pragma unroll
    for (int r = 0; r < 4; ++r)
      st[kf][r] = ok ? st[kf][r] * scale : -1e30f;
  }
  float mx = -1e30f;
#pragma unroll
  for (int kf = 0; kf < 12; ++kf)
#pragma unroll
    for (int r = 0; r < 4; ++r) mx = fmaxf(mx, st[kf][r]);
  mx = fmaxf(mx, __shfl_xor(mx, 16));
  mx = fmaxf(mx, __shfl_xor(mx, 32));
  float s = 0.f;
#pragma unroll
  for (int kf = 0; kf < 12; ++kf)
#pragma unroll
    for (int r = 0; r < 4; ++r) {
      float e = __expf(st[kf][r] - mx);
      st[kf][r] = e;
      s += e;
    }
  s += __shfl_xor(s, 16);
  s += __shfl_xor(s, 32);
  const float inv = 1.f / s;
  __syncthreads();  // bar2: K reads done (P may overwrite), Vt writes visible

  // ---- P write: wave-disjoint rows q = wave*16+lm; compile-time st idx ----
  {
    const int q = wave * 16 + lm;
    ushort* Prow = P_s + q * 192 + (g4 & 1) * 4;
#pragma unroll
    for (int kf = 0; kf < 12; ++kf) {
      uint lo = (uint)f2bf(st[kf][0] * inv) | ((uint)f2bf(st[kf][1] * inv) << 16);
      uint hi = (uint)f2bf(st[kf][2] * inv) | ((uint)f2bf(st[kf][3] * inv) << 16);
      int ck = kf * 2 + (g4 >> 1);
      int cks = ck ^ (lm & 7);            // group-preserving (q&7 == lm&7)
      uint2 val; val.x = lo; val.y = hi;
      *(uint2*)(Prow + cks * 8) = val;
    }
  }
  __syncthreads();  // bar3: P ready

  // ---- PV: wave owns d-block wave*16; out[q][d] for all 4 q-frags ----
  f32x4 ao0 = (f32x4){0.f, 0.f, 0.f, 0.f};
  f32x4 ao1 = (f32x4){0.f, 0.f, 0.f, 0.f};
  f32x4 ao2 = (f32x4){0.f, 0.f, 0.f, 0.f};
  f32x4 ao3 = (f32x4){0.f, 0.f, 0.f, 0.f};
  const int drow = wave * 16 + lm;
  const int dsw = (lm & 7) ^ ((wave * 2 + (lm >> 3)) & 7);
#pragma unroll
  for (int kk = 0; kk < 6; ++kk) {
    int ch = kk * 4 + g4;
    short8 bv = *(const short8*)&Vt_s[drow * 192 + ((ch ^ dsw) * 8)];
    int pch = (ch ^ (lm & 7)) * 8;
    short8 av0 = *(const short8*)&P_s[(0 * 16 + lm) * 192 + pch];
    short8 av1 = *(const short8*)&P_s[(1 * 16 + lm) * 192 + pch];
    short8 av2 = *(const short8*)&P_s[(2 * 16 + lm) * 192 + pch];
    short8 av3 = *(const short8*)&P_s[(3 * 16 + lm) * 192 + pch];
    ao0 = __builtin_amdgcn_mfma_f32_16x16x32_bf16(av0, bv, ao0, 0, 0, 0);
    ao1 = __builtin_amdgcn_mfma_f32_16x16x32_bf16(av1, bv, ao1, 0, 0, 0);
    ao2 = __builtin_amdgcn_mfma_f32_16x16x32_bf16(av2, bv, ao2, 0, 0, 0);
    ao3 = __builtin_amdgcn_mfma_f32_16x16x32_bf16(av3, bv, ao3, 0, 0, 0);
  }
  __syncthreads();  // bar4: PV's Vt/P reads done; O may overwrite Vt region

  // ---- epilogue: O via LDS (stride 68), coalesced bf16 store ----
#pragma unroll
  for (int r = 0; r < 4; ++r) {
    O_s[(0 * 16 + g4 * 4 + r) * 68 + (wave * 16 + lm)] = f2bf(ao0[r]);
    O_s[(1 * 16 + g4 * 4 + r) * 68 + (wave * 16 + lm)] = f2bf(ao1[r]);
    O_s[(2 * 16 + g4 * 4 + r) * 68 + (wave * 16 + lm)] = f2bf(ao2[r]);
    O_s[(3 * 16 + g4 * 4 + r) * 68 + (wave * 16 + lm)] = f2bf(ao3[r]);
  }
  __syncthreads();  // bar5
#pragma unroll
  for (int i = 0; i < 2; ++i) {
    int idx = i * 256 + tid;
    int q = idx >> 3, c = idx & 7;
    short8 v = *(const short8*)&O_s[q * 68 + c * 8];
    int tq = q >> 3, pp = q & 7;
    size_t m = (((size_t)(b * 8 + tq) * 32 + (hb + (pp >> 2))) * 32 + (wb + (pp & 3)));
    *(short8*)(outb + m * (size_t)C_ + n * 64 + c * 8) = v;
  }
}

// ---------------------------------------------------------------------------
extern "C" void kernel_launch(void* const* d_in, const int* in_sizes, int n_in,
                              void* d_out, int out_size, void* d_ws, size_t ws_size,
                              hipStream_t stream) {
  const float* x     = (const float*)d_in[0];
  const float* freqs = (const float*)d_in[1];
  const float* w_in  = (const float*)d_in[2];
  const float* w_out = (const float*)d_in[3];
  const float* qg    = (const float*)d_in[4];
  const float* kg    = (const float*)d_in[5];
  float* out = (float*)d_out;

  char* ws = (char*)d_ws;
  ushort* qkv   = (ushort*)ws;                                    // 50.3 MB bf16
  ushort* xb    = (ushort*)(ws + (size_t)NTOK * C3 * 2);          // 16.8 MB
  ushort* wib   = xb + (size_t)NTOK * C_;                         // 1.5 MB
  ushort* wob   = wib + (size_t)C3 * C_;                          // 0.5 MB
  ushort* attnb = wob + (size_t)C_ * C_;                          // 16.8 MB
  // cos/sin table lives in d_out scratch (2 MB): written by cast3, read by
  // attn, then fully overwritten by gemm2's fp32 output. Stream-ordered.
  float* csn = out;

  // 0) fused casts + sincos table (128 extra blocks)
  cast3_kernel<<<4736, 256, 0, stream>>>(x, w_in, w_out, freqs, xb, wib, wob,
                                         (float2*)csn);

  // 1) qkv = x @ w_in^T (bf16 out, RAW — norm/rope fused into attn).
  //    grid 1536 = 128 bm x 12 bn, XCD-chunked.
  gemm_bt_bf16<true><<<1536, 256, 0, stream>>>(xb, wib, qkv, C3, C_, 12);
  // 2) MFMA neighborhood attention with fused RMSNorm+RoPE -> attnb.
  //    grid 2048 = 2b x 8n x 16th x 8tw.
  attn_kernel<<<2048, 256, 0, stream>>>(qkv, attnb, csn, qg, kg);
  // 3) out = attn @ w_out^T (fp32 out). grid 512 = 128 bm x 4 bn.
  gemm_bt_bf16<false><<<512, 256, 0, stream>>>(attnb, wob, out, C_, C_, 4);
}